// Round 7
// baseline (22825.026 us; speedup 1.0000x reference)
//
#include <hip/hip_runtime.h>
#include <stdint.h>

#define BB 64
#define SS 128   // decoder steps
#define EE 1024  // encoder T
#define HH 512
#define DD 512   // enc_D
#define AA 512
#define VV 128
#define KX 1536  // [emb, ctx, h]
#define NC 2048  // G columns: r | z | gi_n | gh_n (512 each)
#define NKC 6    // GEMM K-split partials
#define NSC 4    // sump partials (et tiles)
#define NCP 4    // ctxp partials (et tiles)
#define NBLK 256 // persistent grid

#define AW_OFF ((size_t)BB*SS*VV)            // 1048576
#define OC_OFF (AW_OFF + (size_t)BB*SS*EE)   // 9437184

typedef unsigned short u16;

__device__ __forceinline__ float sigmoid_f(float x){
  return __builtin_amdgcn_rcpf(1.f + __expf(-x));
}
__device__ __forceinline__ float tanh_f(float x){
  float e = __expf(2.f*x);                 // inf-safe: rcp(inf)=0 -> 1 ; e->0 -> -1
  return 1.f - 2.f*__builtin_amdgcn_rcpf(e + 1.f);
}
__device__ __forceinline__ u16 f2bf(float f){
  uint32_t u = __float_as_uint(f);
  return (u16)((u + 0x7fffu + ((u>>16)&1u)) >> 16);
}

// ---------------- P0: build Wbig, wqT, wvT, fcT, bias_big ----------------
__global__ void k_build(const float* __restrict__ w_ih, const float* __restrict__ w_hh,
                        const float* __restrict__ b_ih, const float* __restrict__ b_hh,
                        const float* __restrict__ wq,   const float* __restrict__ wv,
                        const float* __restrict__ fc_w,
                        float* __restrict__ Wbig, float* __restrict__ wqT,
                        float* __restrict__ wvT,  float* __restrict__ fcT,
                        float* __restrict__ bias_big){
  int i = blockIdx.x*256 + threadIdx.x;
  const int NW = KX*NC;
  if (i < NW){
    int k = i >> 11, c = i & (NC-1);
    float v;
    if (c < 1024)      v = (k < 1024) ? w_ih[c*1024 + k] : w_hh[c*512 + (k-1024)];
    else if (c < 1536) v = (k < 1024) ? w_ih[c*1024 + k] : 0.f;
    else               v = (k >= 1024) ? w_hh[(c-512)*512 + (k-1024)] : 0.f;
    Wbig[i] = v; return;
  }
  i -= NW;
  if (i < 512*512){ int j = i >> 9, a = i & 511; wqT[i] = wq[a*512 + j]; return; }
  i -= 512*512;
  if (i < 512*512){ int e = i >> 9, a = i & 511; wvT[i] = wv[a*512 + e]; return; }
  i -= 512*512;
  if (i < 1024*128){ int k = i >> 7, v = i & 127; fcT[i] = fc_w[v*1024 + k]; return; }
  i -= 1024*128;
  if (i < NC){
    float bv;
    if (i < 1024)      bv = b_ih[i] + b_hh[i];
    else if (i < 1536) bv = b_ih[i];
    else               bv = b_hh[i - 512];
    bias_big[i] = bv;
  }
}

// ---------------- P1: encp = enc @ wvT + (attn_bias+conv_b), bf16 --------
__global__ __launch_bounds__(256) void k_encp(const float* __restrict__ enc,
                                              const float* __restrict__ wvT,
                                              const float* __restrict__ abias,
                                              const float* __restrict__ convb,
                                              u16* __restrict__ encp){
  __shared__ float As[64][36];
  __shared__ float Bs[32][68];
  int tid = threadIdx.x;
  int r0 = blockIdx.x * 64;
  int a0 = blockIdx.y * 64;
  float4 acc[4];
  #pragma unroll
  for (int r = 0; r < 4; ++r) acc[r] = make_float4(0.f,0.f,0.f,0.f);
  int rl = tid >> 2, kl0 = (tid & 3) * 8;
  int kl2 = tid >> 3, al0 = (tid & 7) * 8;
  int br = (tid >> 4) * 4, cc = (tid & 15) * 4;
  for (int kk = 0; kk < 512; kk += 32){
    float4 av0 = *(const float4*)&enc[(size_t)(r0+rl)*512 + kk + kl0];
    float4 av1 = *(const float4*)&enc[(size_t)(r0+rl)*512 + kk + kl0 + 4];
    float4 bv0 = *(const float4*)&wvT[(size_t)(kk+kl2)*512 + a0 + al0];
    float4 bv1 = *(const float4*)&wvT[(size_t)(kk+kl2)*512 + a0 + al0 + 4];
    __syncthreads();
    *(float4*)&As[rl][kl0]     = av0;
    *(float4*)&As[rl][kl0+4]   = av1;
    *(float4*)&Bs[kl2][al0]    = bv0;
    *(float4*)&Bs[kl2][al0+4]  = bv1;
    __syncthreads();
    #pragma unroll
    for (int i = 0; i < 32; ++i){
      float4 b4 = *(const float4*)&Bs[i][cc];
      float x0 = As[br][i], x1 = As[br+1][i], x2 = As[br+2][i], x3 = As[br+3][i];
      acc[0].x += x0*b4.x; acc[0].y += x0*b4.y; acc[0].z += x0*b4.z; acc[0].w += x0*b4.w;
      acc[1].x += x1*b4.x; acc[1].y += x1*b4.y; acc[1].z += x1*b4.z; acc[1].w += x1*b4.w;
      acc[2].x += x2*b4.x; acc[2].y += x2*b4.y; acc[2].z += x2*b4.z; acc[2].w += x2*b4.w;
      acc[3].x += x3*b4.x; acc[3].y += x3*b4.y; acc[3].z += x3*b4.z; acc[3].w += x3*b4.w;
    }
  }
  int a = a0 + cc;
  float b0f = abias[a]   + convb[a];
  float b1f = abias[a+1] + convb[a+1];
  float b2f_ = abias[a+2] + convb[a+2];
  float b3f = abias[a+3] + convb[a+3];
  #pragma unroll
  for (int r = 0; r < 4; ++r){
    size_t row = (size_t)(r0 + br + r);
    ushort4 pk;
    pk.x = f2bf(acc[r].x + b0f);
    pk.y = f2bf(acc[r].y + b1f);
    pk.z = f2bf(acc[r].z + b2f_);
    pk.w = f2bf(acc[r].w + b3f);
    *(ushort4*)&encp[row*512 + a] = pk;
  }
}

// ---------------- P2: enc f32 -> bf16 copy --------------------------------
__global__ __launch_bounds__(256) void k_encbf(const float* __restrict__ enc,
                                               u16* __restrict__ enc_bf){
  size_t i = ((size_t)blockIdx.x*256 + threadIdx.x) * 4;
  float4 v = *(const float4*)&enc[i];
  ushort4 pk;
  pk.x = f2bf(v.x); pk.y = f2bf(v.y); pk.z = f2bf(v.z); pk.w = f2bf(v.w);
  *(ushort4*)&enc_bf[i] = pk;
}

// ---------------- device-scope two-level grid barrier ---------------------
// bar layout (uints): [0..511] 16 L1 counters at stride 32; [512] L2 counter
// (own line via stride); [544] generation.
__device__ __forceinline__ void gbar(unsigned* bar, int bid){
  __syncthreads();
  if (threadIdx.x == 0){
    unsigned* cnt1 = bar + (bid >> 4) * 32;
    unsigned* cnt2 = bar + 512;
    unsigned* gen  = bar + 544;
    unsigned g = __hip_atomic_load(gen, __ATOMIC_RELAXED, __HIP_MEMORY_SCOPE_AGENT);
    unsigned o1 = __hip_atomic_fetch_add(cnt1, 1u, __ATOMIC_ACQ_REL, __HIP_MEMORY_SCOPE_AGENT);
    if (o1 == 15u){
      __hip_atomic_store(cnt1, 0u, __ATOMIC_RELAXED, __HIP_MEMORY_SCOPE_AGENT);
      unsigned o2 = __hip_atomic_fetch_add(cnt2, 1u, __ATOMIC_ACQ_REL, __HIP_MEMORY_SCOPE_AGENT);
      if (o2 == 15u){
        __hip_atomic_store(cnt2, 0u, __ATOMIC_RELAXED, __HIP_MEMORY_SCOPE_AGENT);
        __hip_atomic_store(gen, g + 1u, __ATOMIC_RELEASE, __HIP_MEMORY_SCOPE_AGENT);
      } else {
        while (__hip_atomic_load(gen, __ATOMIC_ACQUIRE, __HIP_MEMORY_SCOPE_AGENT) == g)
          __builtin_amdgcn_s_sleep(2);
      }
    } else {
      while (__hip_atomic_load(gen, __ATOMIC_ACQUIRE, __HIP_MEMORY_SCOPE_AGENT) == g)
        __builtin_amdgcn_s_sleep(2);
    }
  }
  __syncthreads();
}

// ---------------- persistent kernel ---------------------------------------
struct SmA { float Xs[64][36]; float Ws[32][68]; float rs_l[64]; };
struct SmF { float oc[1024]; float lp[2][128]; float ll[128]; };
struct SmB { float h_l[512]; };
struct SmC { float q[512]; float v[512]; float c0[512]; float c1[512];
             float c2[512]; float pw[260]; float ew[256]; float redc[8][512]; };
union Smem { SmA a; SmF f; SmB b; SmC c; };

__device__ __forceinline__ float score8(uint4 pk, float wl, float wc, float wr,
                                        const float* q8, const float* v8,
                                        const float* c08, const float* c18,
                                        const float* c28){
  uint32_t ua[4] = {pk.x, pk.y, pk.z, pk.w};
  float acc = 0.f;
  #pragma unroll
  for (int p = 0; p < 4; ++p){
    float plo = __uint_as_float(ua[p] << 16);
    float phi = __uint_as_float(ua[p] & 0xffff0000u);
    int ii = p*2;
    float x0 = q8[ii]   + plo + c08[ii]*wl   + c18[ii]*wc   + c28[ii]*wr;
    acc += tanh_f(x0) * v8[ii];
    float x1 = q8[ii+1] + phi + c08[ii+1]*wl + c18[ii+1]*wc + c28[ii+1]*wr;
    acc += tanh_f(x1) * v8[ii+1];
  }
  return acc;
}

__global__ __launch_bounds__(512, 2) void k_persist(
    const int* __restrict__ inputs, const float* __restrict__ emb,
    const float* __restrict__ Wbig, const float* __restrict__ biasb,
    const float* __restrict__ wqT,  const float* __restrict__ fcT,
    const float* __restrict__ fcb,  const float* __restrict__ av,
    const float* __restrict__ convw,
    const u16* __restrict__ encp,   const u16* __restrict__ enc_bf,
    float* __restrict__ Gp, float* __restrict__ qp, float* __restrict__ hbuf,
    float* __restrict__ exps0, float* __restrict__ exps1,
    float* __restrict__ sump, float* __restrict__ ctxp,
    float* __restrict__ rs_buf, unsigned* bar, float* __restrict__ out)
{
  __shared__ Smem sm;
  const int tid = threadIdx.x, bid = blockIdx.x;

  for (int s = 0; s < SS; ++s){
    const bool t0 = (s == 0);
    const float* eprev = (s & 1) ? exps0 : exps1;
    float*       ecur  = (s & 1) ? exps1 : exps0;

    // ====== Phase A: GRU GEMM (bid<192, kc-split 6) | fc(s-1) (bid>=192) ==
    if (bid < 192){
      const int c0 = (bid & 31) * 64;
      const int kc = bid >> 5;
      const int kbase = kc * 256;
      if (!t0 && tid < 64){
        float ssum = 0.f;
        #pragma unroll
        for (int p2 = 0; p2 < NSC; ++p2) ssum += sump[p2*64 + tid];
        sm.a.rs_l[tid] = __builtin_amdgcn_rcpf(ssum);
      }
      const int bl = tid >> 3, kl0 = (tid & 7) * 4;   // X stage: 64b x 32k
      const int kw = tid >> 4, cl0 = (tid & 15) * 4;  // W stage: 32k x 64c
      const int br = (tid >> 4) * 2, cc = (tid & 15) * 4; // compute 2b x 4c
      const float* emb_b = emb + (size_t)inputs[bl*SS + s]*HH;
      float4 acc0 = make_float4(0.f,0.f,0.f,0.f);
      float4 acc1 = make_float4(0.f,0.f,0.f,0.f);
      __syncthreads();
      for (int kk = 0; kk < 256; kk += 32){
        float xv[4];
        #pragma unroll
        for (int u = 0; u < 4; ++u){
          int kg = kbase + kk + kl0 + u;
          float v;
          if (kg < 512)       v = emb_b[kg];
          else if (kg < 1024){
            if (t0) v = 0.f;
            else {
              int d = kg - 512;
              float t = 0.f;
              #pragma unroll
              for (int p2 = 0; p2 < NCP; ++p2) t += ctxp[(size_t)(p2*64+bl)*512 + d];
              v = t * sm.a.rs_l[bl];
            }
          }
          else                v = t0 ? 0.f : hbuf[bl*512 + kg - 1024];
          xv[u] = v;
        }
        float4 w1 = *(const float4*)&Wbig[(size_t)(kbase+kk+kw)*NC + c0 + cl0];
        __syncthreads();
        *(float4*)&sm.a.Xs[bl][kl0] = make_float4(xv[0],xv[1],xv[2],xv[3]);
        *(float4*)&sm.a.Ws[kw][cl0] = w1;
        __syncthreads();
        #pragma unroll
        for (int i = 0; i < 32; ++i){
          float4 b4 = *(const float4*)&sm.a.Ws[i][cc];
          float x0 = sm.a.Xs[br][i], x1 = sm.a.Xs[br+1][i];
          acc0.x += x0*b4.x; acc0.y += x0*b4.y; acc0.z += x0*b4.z; acc0.w += x0*b4.w;
          acc1.x += x1*b4.x; acc1.y += x1*b4.y; acc1.z += x1*b4.z; acc1.w += x1*b4.w;
        }
      }
      *(float4*)&Gp[(size_t)(kc*64 + br    )*NC + c0 + cc] = acc0;
      *(float4*)&Gp[(size_t)(kc*64 + br + 1)*NC + c0 + cc] = acc1;
    } else if (!t0){
      // ---- fc for step s-1 ----
      const int b = bid - 192;
      float ssum = 0.f;
      #pragma unroll
      for (int p2 = 0; p2 < NSC; ++p2) ssum += sump[p2*64 + b];
      const float rs = __builtin_amdgcn_rcpf(ssum);
      if (tid == 0) rs_buf[b] = rs;
      if (tid < 256){
        sm.f.oc[tid]     = hbuf[b*512 + tid];
        sm.f.oc[tid+256] = hbuf[b*512 + tid + 256];
        int d0 = tid*2;
        float a0 = 0.f, a1 = 0.f;
        #pragma unroll
        for (int cc2 = 0; cc2 < NCP; ++cc2){
          float2 pv = *(const float2*)&ctxp[(size_t)(cc2*64 + b)*512 + d0];
          a0 += pv.x; a1 += pv.y;
        }
        a0 *= rs; a1 *= rs;
        sm.f.oc[512+d0]   = a0;
        sm.f.oc[512+d0+1] = a1;
        size_t oco = OC_OFF + (size_t)(b*SS + (s-1))*1024 + 512 + d0;
        out[oco]     = a0;
        out[oco + 1] = a1;
      }
      __syncthreads();
      if (tid < 256){
        int v = tid & 127, half = tid >> 7;
        float acc = 0.f;
        #pragma unroll 8
        for (int k = 0; k < 512; ++k)
          acc += sm.f.oc[half*512 + k] * fcT[(size_t)(half*512 + k)*128 + v];
        sm.f.lp[half][v] = acc;
      }
      __syncthreads();
      if (tid < 128) sm.f.ll[tid] = sm.f.lp[0][tid] + sm.f.lp[1][tid] + fcb[tid];
      __syncthreads();
      if (tid < 128){
        float m = -1e30f;
        for (int i = 0; i < 128; ++i) m = fmaxf(m, sm.f.ll[i]);
        float smm = 0.f;
        for (int i = 0; i < 128; ++i) smm += __expf(sm.f.ll[i] - m);
        out[(size_t)(b*SS + (s-1))*VV + tid] = sm.f.ll[tid] - m - __logf(smm);
      }
    }
    gbar(bar, bid);

    // ====== Phase B: gates -> h ; q partials (bid<64) =====================
    if (bid < 64){
      const int jt = bid & 7, bt = bid >> 3;
      const int bi = tid >> 6, jl = tid & 63;
      const int b = bt*8 + bi, j = jt*64 + jl;
      float s0=0.f, s1=0.f, s2=0.f, s3=0.f;
      #pragma unroll
      for (int kc = 0; kc < NKC; ++kc){
        const float* g = Gp + (size_t)(kc*64 + b)*NC;
        s0 += g[j]; s1 += g[512+j]; s2 += g[1024+j]; s3 += g[1536+j];
      }
      float r = sigmoid_f(s0 + biasb[j]);
      float z = sigmoid_f(s1 + biasb[512+j]);
      float n = tanh_f(s2 + biasb[1024+j] + r*(s3 + biasb[1536+j]));
      float hold = t0 ? 0.f : hbuf[b*512 + j];
      float hn = (1.f - z)*n + z*hold;
      sm.b.h_l[tid] = hn;
      hbuf[b*512 + j] = hn;
      out[OC_OFF + (size_t)(b*SS + s)*1024 + j] = hn;
      __syncthreads();
      const int a = tid;
      float acc8[8];
      #pragma unroll
      for (int q2 = 0; q2 < 8; ++q2) acc8[q2] = 0.f;
      for (int jj = 0; jj < 64; ++jj){
        float w = wqT[(size_t)(jt*64 + jj)*512 + a];
        #pragma unroll
        for (int b2 = 0; b2 < 8; ++b2) acc8[b2] += sm.b.h_l[b2*64 + jj]*w;
      }
      #pragma unroll
      for (int b2 = 0; b2 < 8; ++b2)
        qp[(size_t)(jt*64 + bt*8 + b2)*512 + a] = acc8[b2];
    }
    gbar(bar, bid);

    // ====== Phase C: score + exp + aw(s-1) + ctx partials =================
    {
      const int b = bid & 63, et = bid >> 6;   // 4 et tiles x 64 b
      const float rs_prev = t0 ? 0.f : rs_buf[b];
      const float* prev = eprev + (size_t)b*EE;
      {
        float qq = 0.f;
        #pragma unroll
        for (int jt2 = 0; jt2 < 8; ++jt2) qq += qp[(size_t)(jt2*64 + b)*512 + tid];
        sm.c.q[tid]  = qq;
        sm.c.v[tid]  = av[tid];
        sm.c.c0[tid] = convw[tid*3 + 0];
        sm.c.c1[tid] = convw[tid*3 + 1];
        sm.c.c2[tid] = convw[tid*3 + 2];
        if (tid < 258){
          int e = et*256 - 1 + tid;
          float w = 0.f;
          if (!t0 && e >= 0 && e < EE) w = prev[e] * rs_prev;
          sm.c.pw[tid] = w;
        }
      }
      __syncthreads();
      if (!t0 && tid < 256)
        out[AW_OFF + (size_t)(b*SS + (s-1))*EE + et*256 + tid] = sm.c.pw[tid+1];
      const int wave = tid >> 6, lane = tid & 63;
      float q8[8], v8[8], c08[8], c18[8], c28[8];
      #pragma unroll
      for (int i = 0; i < 8; ++i){
        int a = lane*8 + i;
        q8[i] = sm.c.q[a]; v8[i] = sm.c.v[a];
        c08[i] = sm.c.c0[a]; c18[i] = sm.c.c1[a]; c28[i] = sm.c.c2[a];
      }
      const size_t enc_base = ((size_t)b*EE + et*256)*512 + lane*8;
      #pragma unroll 2
      for (int i0 = 0; i0 < 32; i0 += 4){
        const int el = wave*32 + i0;
        uint4 pk0 = *(const uint4*)(encp + enc_base + (size_t)(el  )*512);
        uint4 pk1 = *(const uint4*)(encp + enc_base + (size_t)(el+1)*512);
        uint4 pk2 = *(const uint4*)(encp + enc_base + (size_t)(el+2)*512);
        uint4 pk3 = *(const uint4*)(encp + enc_base + (size_t)(el+3)*512);
        float a0 = score8(pk0, sm.c.pw[el],   sm.c.pw[el+1], sm.c.pw[el+2], q8,v8,c08,c18,c28);
        float a1 = score8(pk1, sm.c.pw[el+1], sm.c.pw[el+2], sm.c.pw[el+3], q8,v8,c08,c18,c28);
        float a2 = score8(pk2, sm.c.pw[el+2], sm.c.pw[el+3], sm.c.pw[el+4], q8,v8,c08,c18,c28);
        float a3 = score8(pk3, sm.c.pw[el+3], sm.c.pw[el+4], sm.c.pw[el+5], q8,v8,c08,c18,c28);
        #pragma unroll
        for (int off = 32; off; off >>= 1){
          a0 += __shfl_xor(a0, off, 64);
          a1 += __shfl_xor(a1, off, 64);
          a2 += __shfl_xor(a2, off, 64);
          a3 += __shfl_xor(a3, off, 64);
        }
        if (lane == 0){
          sm.c.ew[el]   = __expf(a0);   // bounded scores: no max needed
          sm.c.ew[el+1] = __expf(a1);
          sm.c.ew[el+2] = __expf(a2);
          sm.c.ew[el+3] = __expf(a3);
        }
      }
      __syncthreads();
      if (tid < 256) ecur[(size_t)b*EE + et*256 + tid] = sm.c.ew[tid];
      if (tid < 64){
        float t2 = sm.c.ew[tid] + sm.c.ew[tid+64] + sm.c.ew[tid+128] + sm.c.ew[tid+192];
        #pragma unroll
        for (int off = 32; off; off >>= 1) t2 += __shfl_xor(t2, off, 64);
        if (tid == 0) sump[et*64 + b] = t2;
      }
      // ---- ctx partials (enc_bf stream) ----
      const int d0 = lane * 8;
      float acc8[8];
      #pragma unroll
      for (int i = 0; i < 8; ++i) acc8[i] = 0.f;
      const size_t encb_base = ((size_t)b*EE + et*256)*512 + d0;
      #pragma unroll 4
      for (int i = 0; i < 32; ++i){
        int el2 = wave*32 + i;
        uint4 pk = *(const uint4*)(enc_bf + encb_base + (size_t)el2*512);
        float w = sm.c.ew[el2];
        uint32_t ua[4] = {pk.x, pk.y, pk.z, pk.w};
        #pragma unroll
        for (int p = 0; p < 4; ++p){
          acc8[p*2]   += w * __uint_as_float(ua[p] << 16);
          acc8[p*2+1] += w * __uint_as_float(ua[p] & 0xffff0000u);
        }
      }
      #pragma unroll
      for (int i = 0; i < 8; ++i) sm.c.redc[wave][d0 + i] = acc8[i];
      __syncthreads();
      if (tid < 128){
        int d = tid * 4;
        float4 t = make_float4(0.f,0.f,0.f,0.f);
        #pragma unroll
        for (int w2 = 0; w2 < 8; ++w2){
          float4 r4 = *(const float4*)&sm.c.redc[w2][d];
          t.x += r4.x; t.y += r4.y; t.z += r4.z; t.w += r4.w;
        }
        *(float4*)&ctxp[(size_t)(et*64 + b)*512 + d] = t;
      }
    }
    gbar(bar, bid);
  }

  // ====== Tail: aw(127) + fc(127) (bid<64) ================================
  if (bid < 64){
    const int b = bid;
    const float* efin = exps1;   // s=127 odd -> cur = exps1
    float ssum = 0.f;
    #pragma unroll
    for (int p2 = 0; p2 < NSC; ++p2) ssum += sump[p2*64 + b];
    const float rs = __builtin_amdgcn_rcpf(ssum);
    if (tid < 256){
      #pragma unroll
      for (int i = 0; i < 4; ++i){
        int e = i*256 + tid;
        out[AW_OFF + (size_t)(b*SS + (SS-1))*EE + e] = efin[(size_t)b*EE + e] * rs;
      }
      sm.f.oc[tid]     = hbuf[b*512 + tid];
      sm.f.oc[tid+256] = hbuf[b*512 + tid + 256];
      int d0 = tid*2;
      float a0 = 0.f, a1 = 0.f;
      #pragma unroll
      for (int cc2 = 0; cc2 < NCP; ++cc2){
        float2 pv = *(const float2*)&ctxp[(size_t)(cc2*64 + b)*512 + d0];
        a0 += pv.x; a1 += pv.y;
      }
      a0 *= rs; a1 *= rs;
      sm.f.oc[512+d0]   = a0;
      sm.f.oc[512+d0+1] = a1;
      size_t oco = OC_OFF + (size_t)(b*SS + (SS-1))*1024 + 512 + d0;
      out[oco]     = a0;
      out[oco + 1] = a1;
    }
    __syncthreads();
    if (tid < 256){
      int v = tid & 127, half = tid >> 7;
      float acc = 0.f;
      #pragma unroll 8
      for (int k = 0; k < 512; ++k)
        acc += sm.f.oc[half*512 + k] * fcT[(size_t)(half*512 + k)*128 + v];
      sm.f.lp[half][v] = acc;
    }
    __syncthreads();
    if (tid < 128) sm.f.ll[tid] = sm.f.lp[0][tid] + sm.f.lp[1][tid] + fcb[tid];
    __syncthreads();
    if (tid < 128){
      float m = -1e30f;
      for (int i = 0; i < 128; ++i) m = fmaxf(m, sm.f.ll[i]);
      float smm = 0.f;
      for (int i = 0; i < 128; ++i) smm += __expf(sm.f.ll[i] - m);
      out[(size_t)(b*SS + (SS-1))*VV + tid] = sm.f.ll[tid] - m - __logf(smm);
    }
  }
}

extern "C" void kernel_launch(void* const* d_in, const int* in_sizes, int n_in,
                              void* d_out, int out_size, void* d_ws, size_t ws_size,
                              hipStream_t stream){
  (void)in_sizes; (void)n_in; (void)out_size; (void)ws_size;
  const int*   inputs = (const int*)d_in[0];
  const float* enc    = (const float*)d_in[1];
  const float* emb    = (const float*)d_in[2];
  const float* w_ih   = (const float*)d_in[3];
  const float* w_hh   = (const float*)d_in[4];
  const float* b_ih   = (const float*)d_in[5];
  const float* b_hh   = (const float*)d_in[6];
  const float* wq     = (const float*)d_in[7];
  const float* wv     = (const float*)d_in[8];
  const float* convw  = (const float*)d_in[9];
  const float* convb  = (const float*)d_in[10];
  const float* abias  = (const float*)d_in[11];
  const float* av     = (const float*)d_in[12];
  const float* fcw    = (const float*)d_in[13];
  const float* fcb    = (const float*)d_in[14];
  float* out = (float*)d_out;

  char* p = (char*)d_ws;
  auto alloc = [&](size_t bytes)->char*{
    char* r = p; p += (bytes + 255) & ~(size_t)255; return r;
  };
  u16*   encp   = (u16*)  alloc((size_t)BB*EE*AA*2);   // 67 MB
  u16*   enc_bf = (u16*)  alloc((size_t)BB*EE*DD*2);   // 67 MB
  float* Wbig   = (float*)alloc((size_t)KX*NC*4);      // 12.6 MB
  float* wqT    = (float*)alloc((size_t)512*512*4);
  float* wvT    = (float*)alloc((size_t)512*512*4);
  float* fcT    = (float*)alloc((size_t)1024*128*4);
  float* biasb  = (float*)alloc((size_t)NC*4);
  float* hbuf   = (float*)alloc((size_t)BB*HH*4);
  float* Gp     = (float*)alloc((size_t)NKC*BB*NC*4);  // 3 MB
  float* qp     = (float*)alloc((size_t)8*BB*AA*4);    // 1 MB
  float* exps0  = (float*)alloc((size_t)BB*EE*4);      // 256 KB
  float* exps1  = (float*)alloc((size_t)BB*EE*4);      // 256 KB
  float* sump   = (float*)alloc((size_t)NSC*BB*4);
  float* ctxp   = (float*)alloc((size_t)NCP*BB*DD*4);  // 512 KB
  float* rs_buf = (float*)alloc((size_t)BB*4);
  unsigned* bar = (unsigned*)alloc(4096);

  hipMemsetAsync(bar, 0, 4096, stream);
  int total0 = KX*NC + 512*512 + 512*512 + 1024*128 + NC;
  k_build<<<(total0 + 255)/256, 256, 0, stream>>>(w_ih, w_hh, b_ih, b_hh, wq, wv, fcw,
                                                  Wbig, wqT, wvT, fcT, biasb);
  k_encp<<<dim3(1024, 8), 256, 0, stream>>>(enc, wvT, abias, convb, encp);
  k_encbf<<<(BB*EE*DD/4 + 255)/256, 256, 0, stream>>>(enc, enc_bf);

  k_persist<<<NBLK, 512, 0, stream>>>(inputs, emb, Wbig, biasb, wqT, fcT, fcb,
                                      av, convw, encp, enc_bf,
                                      Gp, qp, hbuf, exps0, exps1,
                                      sump, ctxp, rs_buf, bar, out);
}